// Round 11
// baseline (919.853 us; speedup 1.0000x reference)
//
#include <hip/hip_runtime.h>
#include <stdint.h>
#include <math.h>

// MetropolisHastingsSampler: 2176-step serial MH chain, D=512, H=1024.
//   K1: RNG (bit-exact JAX threefry, partitionable mode) -> A, U.
//   K2: Z = A @ W1 (f64 accumulate), 16 rows x 2 cols / thread, 137 blocks.
//   K3: block 0 = chain, 2 steps per barrier (R10 scheme: 3 candidate psis
//       E1=Y+Za, E2=Y+Zb, E3=(Y+Za)+Zb per iter), but with 512 THREADS
//       (2 H-cols/thread): fitted model (R8 vs R10) gives per-eval cost
//       E~300cyc at 4 cols/thread, barrier fixed cost B0~410; halving eval
//       width halves E's issue part. Reader sums 8 wave-partials.
//       blocks 1..255 = DVFS-keeper fillers (R9 probe: ~2.14 GHz sustained).
// Workspace: A(2184x512) | Z(2184x1024) | U(2184) | flag  ~= 12.8 MiB.

#define T_TOTAL 2176
#define NITER   1088
#define NROWS   2177
#define NBURN   128
#define DDIM    512
#define HDIM    1024
#define DONE_FLAG 0x13572468u

// ---------------- threefry2x32 (JAX-exact) ----------------
__device__ __forceinline__ uint2 tf2x32(uint32_t k0, uint32_t k1,
                                        uint32_t x0, uint32_t x1) {
  uint32_t ks2 = k0 ^ k1 ^ 0x1BD11BDAu;
  x0 += k0; x1 += k1;
#define TF_R(r) { x0 += x1; x1 = (x1 << (r)) | (x1 >> (32 - (r))); x1 ^= x0; }
  TF_R(13) TF_R(15) TF_R(26) TF_R(6)
  x0 += k1;  x1 += ks2 + 1u;
  TF_R(17) TF_R(29) TF_R(16) TF_R(24)
  x0 += ks2; x1 += k0 + 2u;
  TF_R(13) TF_R(15) TF_R(26) TF_R(6)
  x0 += k0;  x1 += k1 + 3u;
  TF_R(17) TF_R(29) TF_R(16) TF_R(24)
  x0 += k1;  x1 += ks2 + 4u;
  TF_R(13) TF_R(15) TF_R(26) TF_R(6)
  x0 += ks2; x1 += k0 + 5u;
#undef TF_R
  return make_uint2(x0, x1);
}

// ---------------- XLA ErfInv f32 (Giles polynomial) ----------------
__device__ __forceinline__ float erfinv_xla(float x) {
  float w = -log1pf(-x * x);
  float p;
  if (w < 5.0f) {
    w = w - 2.5f;
    p = 2.81022636e-08f;
    p = fmaf(p, w, 3.43273939e-07f);
    p = fmaf(p, w, -3.5233877e-06f);
    p = fmaf(p, w, -4.39150654e-06f);
    p = fmaf(p, w, 0.00021858087f);
    p = fmaf(p, w, -0.00125372503f);
    p = fmaf(p, w, -0.00417768164f);
    p = fmaf(p, w, 0.246640727f);
    p = fmaf(p, w, 1.50140941f);
  } else {
    w = sqrtf(w) - 3.0f;
    p = -0.000200214257f;
    p = fmaf(p, w, 0.000100950558f);
    p = fmaf(p, w, 0.00134934322f);
    p = fmaf(p, w, -0.00367342844f);
    p = fmaf(p, w, 0.00573950773f);
    p = fmaf(p, w, -0.0076224613f);
    p = fmaf(p, w, 0.00943887047f);
    p = fmaf(p, w, 1.00167406f);
    p = fmaf(p, w, 2.83297682f);
  }
  return p * x;
}

__device__ __forceinline__ float normal_from_bits(uint32_t bits) {
  const float lo = -0.99999994f;  // -(1 - 2^-24)
  float u01 = __uint_as_float(0x3f800000u | (bits >> 9)) - 1.0f;
  float v = u01 * 2.0f + lo;
  v = fmaxf(lo, v);
  return 1.41421356237309515f * erfinv_xla(v);
}

// ---------------- fast tanh via hardware exp2 ----------------
__device__ __forceinline__ float tanh_fast(float x) {
  float a = x * 2.88539008177792681472f;       // 2*log2(e)
#if __has_builtin(__builtin_amdgcn_exp2f)
  float e = __builtin_amdgcn_exp2f(a);
#else
  float e = exp2f(a);
#endif
  float r = __builtin_amdgcn_rcpf(e + 1.0f);
  return fmaf(-2.0f, r, 1.0f);
}

// ---------------- K1: RNG (threefry partitionable mode) ----------------
__global__ void __launch_bounds__(256) rng_kernel(const float* __restrict__ x0,
                                                  float* __restrict__ A,
                                                  float* __restrict__ U) {
  const uint32_t t = blockIdx.x;
  const int tid = threadIdx.x;
  uint2 kt = tf2x32(0u, 1u, 0u, t);
  uint2 kn = tf2x32(kt.x, kt.y, 0u, 0u);
  uint2 e0 = tf2x32(kn.x, kn.y, 0u, (uint32_t)tid);
  uint2 e1 = tf2x32(kn.x, kn.y, 0u, (uint32_t)(tid + 256));
  float n0 = normal_from_bits(e0.x ^ e0.y);
  float n1 = normal_from_bits(e1.x ^ e1.y);
  float* Arow = A + (size_t)(t + 1) * DDIM;
  Arow[tid]       = n0 * 0.1f;
  Arow[tid + 256] = n1 * 0.1f;
  if (tid == 0) {
    uint2 ku = tf2x32(kt.x, kt.y, 0u, 1u);
    uint2 eu = tf2x32(ku.x, ku.y, 0u, 0u);
    U[t] = __uint_as_float(0x3f800000u | ((eu.x ^ eu.y) >> 9)) - 1.0f;
  }
  if (t == 0) {
    A[tid]       = x0[tid];
    A[tid + 256] = x0[tid + 256];
  }
}

// ---------------- K2: Z = A @ W1 (f64 accumulate), 16 rows/block ------------
__global__ void __launch_bounds__(512) gemm_kernel(const float* __restrict__ A,
                                                   const float* __restrict__ W1,
                                                   float* __restrict__ Z,
                                                   int nrows) {
  const int r0 = blockIdx.x * 16;
  const int t  = threadIdx.x;          // 0..511
  const int c0 = t, c1 = t + 512;
  double acc[16][2];
#pragma unroll
  for (int r = 0; r < 16; ++r) { acc[r][0] = 0.0; acc[r][1] = 0.0; }
  for (int d = 0; d < 512; d += 4) {
    double wA[4], wB[4];
#pragma unroll
    for (int j = 0; j < 4; ++j) {
      wA[j] = (double)W1[(size_t)(d + j) * 1024 + c0];
      wB[j] = (double)W1[(size_t)(d + j) * 1024 + c1];
    }
#pragma unroll
    for (int r = 0; r < 16; ++r) {
      int rr = r0 + r; if (rr >= nrows) rr = nrows - 1;   // uniform clamp
      const float4 a4 = *(const float4*)(A + (size_t)rr * 512 + d);
      double a0 = (double)a4.x, a1 = (double)a4.y;
      double a2 = (double)a4.z, a3 = (double)a4.w;
      acc[r][0] += (a0 * wA[0] + a1 * wA[1]) + (a2 * wA[2] + a3 * wA[3]);
      acc[r][1] += (a0 * wB[0] + a1 * wB[1]) + (a2 * wB[2] + a3 * wB[3]);
    }
  }
  const int rmax = (nrows - r0 < 16) ? (nrows - r0) : 16;
  for (int r = 0; r < rmax; ++r) {
    Z[(size_t)(r0 + r) * 1024 + c0] = (float)acc[r][0];
    Z[(size_t)(r0 + r) * 1024 + c1] = (float)acc[r][1];
  }
}

// ---------------- DPP wave64 sum-reduce (result in lane 63) ----------------
#define DPP_ADD(v, ctrl)                                                     \
  v += __int_as_float(__builtin_amdgcn_update_dpp(                           \
      0, __float_as_int(v), (ctrl), 0xF, 0xF, true))

__device__ __forceinline__ float wave_reduce_to_last(float v) {
  DPP_ADD(v, 0xB1);   // quad_perm xor1
  DPP_ADD(v, 0x4E);   // quad_perm xor2
  DPP_ADD(v, 0x141);  // row_half_mirror
  DPP_ADD(v, 0x140);  // row_mirror -> row16 totals
  DPP_ADD(v, 0x142);  // row_bcast15
  DPP_ADD(v, 0x143);  // row_bcast31 -> lane 63 wave total
  return v;
}

// Execution barrier with LDS-visibility only (no vmcnt drain).
#define BAR() asm volatile("s_waitcnt lgkmcnt(0)\n\ts_barrier" ::: "memory")

// ---------------- K3: 2-steps-per-barrier chain, 512 thr + fillers ---------
__global__ void __launch_bounds__(512) chain_kernel(
    const float* __restrict__ Z, const float* __restrict__ A,
    const float* __restrict__ U, const float* __restrict__ x0,
    const float* __restrict__ b1, const float* __restrict__ W2,
    const float* __restrict__ b2, float* __restrict__ out,
    unsigned* __restrict__ flag) {
  const int tid = threadIdx.x;

  if (blockIdx.x != 0) {
    // DVFS keeper: bounded latency-bound fma spin; exits on flag.
    float acc = (float)tid * 1.0e-6f;
    for (int i = 0; i < 4000; ++i) {
#pragma unroll
      for (int jj = 0; jj < 256; ++jj) acc = fmaf(acc, 0.99999988f, 1.0e-7f);
      unsigned f = __hip_atomic_load(flag, __ATOMIC_RELAXED,
                                     __HIP_MEMORY_SCOPE_AGENT);
      if (f == DONE_FLAG) break;
    }
    if (acc == 123456.75f && tid == 1023) out[0] = acc;  // never true
    return;
  }

  const int lane = tid & 63;
  const int wid = tid >> 6;              // 0..7
  // wsum[slot][eval 0=E1,1=E2,2=E3][wave 0..7]
  __shared__ __align__(16) float wsum[2][3][8];
  __shared__ float Uld[2184];

  const float2* Zv = (const float2*)Z;   // 512 float2 per H-row
  // delta element for this thread: A[row*512 + tid]

  for (int i = tid; i < 2184; i += 512) Uld[i] = U[i];

  const float2 w2v = ((const float2*)W2)[tid];
  const float2 b1v = ((const float2*)b1)[tid];
  const float b2v = b2[0];

  // prologue loads
  float2 z0r = Zv[tid];                          // Z row 0
  float2 z1r = Zv[512 + tid];                    // Z row 1
  float2 z2r = Zv[1024 + tid];                   // Z row 2
  float2 zA0 = Zv[3 * 512 + tid], zB0 = Zv[4 * 512 + tid];   // rows 3,4
  float2 zA1 = Zv[5 * 512 + tid], zB1 = Zv[6 * 512 + tid];   // rows 5,6
  float dAa0 = A[1 * 512 + tid], dAb0 = A[2 * 512 + tid];    // rows 1,2
  float dAa1 = A[3 * 512 + tid], dAb1 = A[4 * 512 + tid];    // rows 3,4

  double Y0 = (double)z0r.x + (double)b1v.x;
  double Y1 = (double)z0r.y + (double)b1v.y;

  float xa = x0[tid];

  __syncthreads();                       // Uld visible

  // ---- prologue: p = psi2(x0) (slot 1 / eval 0 as scratch) ----
  {
    float g0 = tanh_fast((float)Y0);
    float g1 = tanh_fast((float)Y1);
    float tm = fmaf(g1, w2v.y, g0 * w2v.x);
    tm = wave_reduce_to_last(tm);
    if (lane == 63) wsum[1][0][wid] = tm;
  }
  __syncthreads();
  float p;
  {
    const float4 qa = *(const float4*)&wsum[1][0][0];
    const float4 qb = *(const float4*)&wsum[1][0][4];
    float m0 = (((qa.x + qa.y) + (qa.z + qa.w)) +
                ((qb.x + qb.y) + (qb.z + qb.w))) + b2v;
    p = m0 * m0;
  }
  float um1 = Uld[0] * (p + 1e-12f);
  float u2c = Uld[1];

  // ---- prologue: evals for iter 0 (candidates rows 1,2) -> slot 0 ----
  double Ya0 = Y0 + (double)z1r.x, Ya1 = Y1 + (double)z1r.y;
  double Yb0 = Y0 + (double)z2r.x, Yb1 = Y1 + (double)z2r.y;
  double Yc0 = Ya0 + (double)z2r.x, Yc1 = Ya1 + (double)z2r.y;
  {
    float a0 = tanh_fast((float)Ya0), a1 = tanh_fast((float)Ya1);
    float b0 = tanh_fast((float)Yb0), b1_ = tanh_fast((float)Yb1);
    float c0 = tanh_fast((float)Yc0), c1 = tanh_fast((float)Yc1);
    float tA = fmaf(a1, w2v.y, a0 * w2v.x);
    float tB = fmaf(b1_, w2v.y, b0 * w2v.x);
    float tC = fmaf(c1, w2v.y, c0 * w2v.x);
    tA = wave_reduce_to_last(tA);
    tB = wave_reduce_to_last(tB);
    tC = wave_reduce_to_last(tC);
    if (lane == 63) {
      wsum[0][0][wid] = tA;
      wsum[0][1][wid] = tB;
      wsum[0][2][wid] = tC;
    }
  }
  __syncthreads();

  // Per-iteration macro: decisions for steps t=2k, 2k+1. PAR = k&1.
#define ITER(k, PAR, ZAB, ZBB, DAB, DBB)                                     \
  {                                                                          \
    float u1n = Uld[2 * (k) + 2];                                            \
    float u2n = Uld[2 * (k) + 3];                                            \
    const float4 e1a = *(const float4*)&wsum[PAR][0][0];                     \
    const float4 e1b = *(const float4*)&wsum[PAR][0][4];                     \
    const float4 e2a = *(const float4*)&wsum[PAR][1][0];                     \
    const float4 e2b = *(const float4*)&wsum[PAR][1][4];                     \
    const float4 e3a = *(const float4*)&wsum[PAR][2][0];                     \
    const float4 e3b = *(const float4*)&wsum[PAR][2][4];                     \
    float m1 = (((e1a.x + e1a.y) + (e1a.z + e1a.w)) +                        \
                ((e1b.x + e1b.y) + (e1b.z + e1b.w))) + b2v;                  \
    float q1 = m1 * m1;                                                      \
    bool a1v = um1 < q1;                                                     \
    float p1 = a1v ? q1 : p;                                                 \
    float um2 = u2c * (p1 + 1e-12f);                                         \
    float m2v = (((e2a.x + e2a.y) + (e2a.z + e2a.w)) +                       \
                 ((e2b.x + e2b.y) + (e2b.z + e2b.w))) + b2v;                 \
    float m3v = (((e3a.x + e3a.y) + (e3a.z + e3a.w)) +                       \
                 ((e3b.x + e3b.y) + (e3b.z + e3b.w))) + b2v;                 \
    float m23 = a1v ? m3v : m2v;                                             \
    float q23 = m23 * m23;                                                   \
    bool a2v = um2 < q23;                                                    \
    p = a2v ? q23 : p1;                                                      \
    float xat = a1v ? xa + DAB : xa;                                         \
    xa = a2v ? xat + DBB : xat;                                              \
    if ((k) >= 64) {                                                         \
      out[(size_t)(2 * (k) - NBURN) * DDIM + tid] = xat;                     \
      out[(size_t)(2 * (k) + 1 - NBURN) * DDIM + tid] = xa;                  \
    }                                                                        \
    DAB = A[(size_t)(2 * (k) + 5) * 512 + tid];                              \
    DBB = A[(size_t)(2 * (k) + 6) * 512 + tid];                              \
    Y0 = a1v ? (a2v ? Yc0 : Ya0) : (a2v ? Yb0 : Y0);                         \
    Y1 = a1v ? (a2v ? Yc1 : Ya1) : (a2v ? Yb1 : Y1);                         \
    Ya0 = Y0 + (double)ZAB.x;  Ya1 = Y1 + (double)ZAB.y;                     \
    Yb0 = Y0 + (double)ZBB.x;  Yb1 = Y1 + (double)ZBB.y;                     \
    Yc0 = Ya0 + (double)ZBB.x; Yc1 = Ya1 + (double)ZBB.y;                    \
    ZAB = Zv[(size_t)(2 * (k) + 7) * 512 + tid];                             \
    ZBB = Zv[(size_t)(2 * (k) + 8) * 512 + tid];                             \
    float ga0 = tanh_fast((float)Ya0), ga1 = tanh_fast((float)Ya1);          \
    float gb0 = tanh_fast((float)Yb0), gb1 = tanh_fast((float)Yb1);          \
    float gc0 = tanh_fast((float)Yc0), gc1 = tanh_fast((float)Yc1);          \
    float tA = fmaf(ga1, w2v.y, ga0 * w2v.x);                                \
    float tB = fmaf(gb1, w2v.y, gb0 * w2v.x);                                \
    float tC = fmaf(gc1, w2v.y, gc0 * w2v.x);                                \
    tA = wave_reduce_to_last(tA);                                            \
    tB = wave_reduce_to_last(tB);                                            \
    tC = wave_reduce_to_last(tC);                                            \
    if (lane == 63) {                                                        \
      wsum[(PAR) ^ 1][0][wid] = tA;                                          \
      wsum[(PAR) ^ 1][1][wid] = tB;                                          \
      wsum[(PAR) ^ 1][2][wid] = tC;                                          \
    }                                                                        \
    um1 = u1n * (p + 1e-12f);                                                \
    u2c = u2n;                                                               \
    BAR();                                                                   \
  }

  for (int k = 0; k < NITER; k += 2) {
    ITER(k,     0, zA0, zB0, dAa0, dAb0);
    ITER(k + 1, 1, zA1, zB1, dAa1, dAb1);
  }
#undef ITER

  if (tid == 0) {
    __hip_atomic_store(flag, DONE_FLAG, __ATOMIC_RELAXED,
                       __HIP_MEMORY_SCOPE_AGENT);
  }
}

extern "C" void kernel_launch(void* const* d_in, const int* in_sizes, int n_in,
                              void* d_out, int out_size, void* d_ws, size_t ws_size,
                              hipStream_t stream) {
  const float* x0 = (const float*)d_in[0];
  const float* W1 = (const float*)d_in[1];
  const float* b1 = (const float*)d_in[2];
  const float* W2 = (const float*)d_in[3];
  const float* b2 = (const float*)d_in[4];
  float* out = (float*)d_out;

  char* ws = (char*)d_ws;
  // A: 2184 x 512 f32 = 4,472,832 B ; Z: 2184 x 1024 f32 = 8,945,664 B ;
  // U: 2184 f32 = 8,736 B ; flag 4 B.
  float* A = (float*)ws;
  float* Z = (float*)(ws + 4472832);
  float* U = (float*)(ws + 4472832 + 8945664);
  unsigned* flag = (unsigned*)(ws + 4472832 + 8945664 + 8736);

  rng_kernel<<<T_TOTAL, 256, 0, stream>>>(x0, A, U);
  gemm_kernel<<<137, 512, 0, stream>>>(A, W1, Z, NROWS);
  chain_kernel<<<256, 512, 0, stream>>>(Z, A, U, x0, b1, W2, b2, out, flag);
}